// Round 16
// baseline (309.102 us; speedup 1.0000x reference)
//
#include <hip/hip_runtime.h>
#include <hip/hip_bf16.h>
#include <stdint.h>

typedef __bf16 bf16x8 __attribute__((ext_vector_type(8)));
typedef float f32x4 __attribute__((ext_vector_type(4)));
typedef unsigned short ushort_t;
typedef ushort_t ushort8 __attribute__((ext_vector_type(8)));

#define GLDS16(g, l) __builtin_amdgcn_global_load_lds(                          \
    (const __attribute__((address_space(1))) void*)(g),                         \
    (__attribute__((address_space(3))) void*)(l), 16, 0, 0)

__device__ __constant__ float NF4_LUT_C[16] = {
    -1.0f, -0.6961928009986877f, -0.5250730514526367f, -0.39491748809814453f,
    -0.28444138169288635f, -0.18477343022823334f, -0.09105003625154495f, 0.0f,
    0.07958029955625534f, 0.16093020141124725f, 0.24611230194568634f,
    0.33791524171829224f, 0.44070982933044434f, 0.5626170039176941f,
    0.7229568362236023f, 1.0f};

__device__ inline ushort_t f32_to_bf16(float f) {
    uint32_t u = __builtin_bit_cast(uint32_t, f);
    u += 0x7FFFu + ((u >> 16) & 1u);
    return (ushort_t)(u >> 16);
}

// ---------------------------------------------------------------------------
// Merged prep: blocks 0..16383 cast x -> linear bf16 xb (8 elems/thread);
// blocks 16384..17407 NF4-dequant -> Wt[n][k] bf16 with 256k x 64n tiles:
// each thread writes 8 x 16B contiguous (128B), 4-thread groups 512B
// contiguous -> 4x wider write segments than the 64x64 tiling (r15's
// prep was ~14 us slower than packed; this recovers it at same Wt layout).
// ---------------------------------------------------------------------------
__global__ __launch_bounds__(256) void prep_kernel(
    const float* __restrict__ x, const int* __restrict__ q,
    const float* __restrict__ scales,
    ushort_t* __restrict__ xb, ushort_t* __restrict__ Wt)
{
    __shared__ float lut[16];
    __shared__ ushort_t tile[256][68];   // [k_local][n_local], padded
    const int t   = threadIdx.x;
    const int bid = blockIdx.x;

    if (bid < 16384) {
        // ---------------- cast part (r15-verified) ----------------
        const int i = bid * 256 + t;   // 8 elements per thread
        const float4* p = reinterpret_cast<const float4*>(x);
        float4 a = p[(size_t)i * 2];
        float4 b = p[(size_t)i * 2 + 1];
        ushort8 v;
        v[0] = f32_to_bf16(a.x); v[1] = f32_to_bf16(a.y);
        v[2] = f32_to_bf16(a.z); v[3] = f32_to_bf16(a.w);
        v[4] = f32_to_bf16(b.x); v[5] = f32_to_bf16(b.y);
        v[6] = f32_to_bf16(b.z); v[7] = f32_to_bf16(b.w);
        *reinterpret_cast<ushort8*>(xb + (size_t)i * 8) = v;
    } else {
        // -------- dequant + transpose part: 256k x 64n per block --------
        const int bid2 = bid - 16384;      // 0..1023
        const int nt = bid2 & 63;          // 64-col n tile
        const int kt = bid2 >> 6;          // 0..15, 256-row k tile
        if (t < 16) lut[t] = NF4_LUT_C[t];
        __syncthreads();

        // reads: 2048 int4 total; thread L handles k-row L>>3, quad L&7
        #pragma unroll
        for (int it = 0; it < 8; ++it) {
            const int L  = t + it * 256;
            const int r  = L >> 3;         // k_local 0..255
            const int qd = L & 7;
            const int k  = kt * 256 + r;
            const int4 e4 = *reinterpret_cast<const int4*>(q + (size_t)k * 2048 + nt * 32 + qd * 4);
            const float s = scales[k * 64 + nt];
            const int nb = qd * 8;
            int bts[4] = {e4.x, e4.y, e4.z, e4.w};
            #pragma unroll
            for (int e = 0; e < 4; ++e) {
                const int byte = bts[e];
                tile[r][nb + e * 2]     = f32_to_bf16(lut[(byte >> 4) & 0xF] * s);
                tile[r][nb + e * 2 + 1] = f32_to_bf16(lut[byte & 0xF] * s);
            }
        }
        __syncthreads();

        // writes: thread -> n_local = t>>2, k-chunk (t&3)*64; 8 x 16B = 128B
        const int nl = t >> 2;
        const int kc = (t & 3) * 64;
        ushort_t* dst = Wt + (size_t)(nt * 64 + nl) * 4096 + kt * 256 + kc;
        #pragma unroll
        for (int j = 0; j < 8; ++j) {
            ushort8 v;
            #pragma unroll
            for (int e = 0; e < 8; ++e) v[e] = tile[kc + j * 8 + e][nl];
            *reinterpret_cast<ushort8*>(dst + j * 8) = v;
        }
    }
}

// ---------------------------------------------------------------------------
// GEMM: r4 verbatim (best measured: 273.4 us, MfmaUtil 44.7%, 0 bank
// conflicts). 256x256 tile, BK=32, 8 waves (2M x 4N), 16x16x32 MFMA.
// 4-slot LDS ring, depth-3 prefetch, counted vmcnt(8)/4/0, ONE barrier per
// K32-tile. Slot swizzle phys_slot = slot ^ ((row>>1)&3), both-sides (linear
// global_load_lds dest, pre-swizzled global src, swizzled per-lane read).
// ---------------------------------------------------------------------------
__global__ __launch_bounds__(512, 2) void gemm_nf4_kernel(
    const ushort_t* __restrict__ A, const ushort_t* __restrict__ Bt,
    const float* __restrict__ bias, float* __restrict__ C)
{
    __shared__ __align__(16) ushort_t As[4][256 * 32];
    __shared__ __align__(16) ushort_t Bs[4][256 * 32];

    const int tid  = threadIdx.x;
    const int lane = tid & 63;
    const int wid  = tid >> 6;        // 0..7
    const int wr   = wid >> 2;        // 0..1 -> 128-row A strip
    const int wc   = wid & 3;         // 0..3 -> 64-row B strip
    const int ln15 = lane & 15;
    const int lq   = lane >> 4;       // 0..3 (16B k-slot)

    // XCD-aware bijective swizzle (512 % 8 == 0)
    const int wg  = blockIdx.x;
    const int swz = (wg & 7) * 64 + (wg >> 3);
    const int m0  = (swz >> 4) * 256;   // 32 m-tiles
    const int n0  = (swz & 15) * 256;   // 16 n-tiles

    // staging: LDS row wid*16 + (lane>>2), linear dest; global src k pre-swizzled
    const int srow = wid * 16 + (lane >> 2);
    const int scol = ((lane & 3) ^ ((lane >> 3) & 3)) * 8;
    const ushort_t* gA0 = A  + (size_t)(m0 + srow) * 4096 + scol;
    const ushort_t* gA1 = gA0 + (size_t)128 * 4096;
    const ushort_t* gB0 = Bt + (size_t)(n0 + srow) * 4096 + scol;
    const ushort_t* gB1 = gB0 + (size_t)128 * 4096;
    const int ldsOff0 = (wid * 16) * 32;
    const int ldsOff1 = (128 + wid * 16) * 32;

    f32x4 acc[8][4];
    #pragma unroll
    for (int i = 0; i < 8; ++i)
        #pragma unroll
        for (int j = 0; j < 4; ++j)
            acc[i][j] = (f32x4){0.f, 0.f, 0.f, 0.f};

    // fragment read bases; swizzled k-slot offset is per-lane constant
    const int po  = ((lq ^ ((ln15 >> 1) & 3)) << 3);
    const int rdA = (wr * 128 + ln15) * 32 + po;
    const int rdB = (wc * 64  + ln15) * 32 + po;

    // prologue: stage tiles 0,1,2 into slots 0,1,2; wait tile 0
    #pragma unroll
    for (int tt = 0; tt < 3; ++tt) {
        const int kof = tt * 32;
        GLDS16(gA0 + kof, &As[tt][ldsOff0]);
        GLDS16(gA1 + kof, &As[tt][ldsOff1]);
        GLDS16(gB0 + kof, &Bs[tt][ldsOff0]);
        GLDS16(gB1 + kof, &Bs[tt][ldsOff1]);
    }
    asm volatile("s_waitcnt vmcnt(8)" ::: "memory");
    __builtin_amdgcn_s_barrier();
    __builtin_amdgcn_sched_barrier(0);

    for (int t = 0; t < 128; ++t) {
        const int slot = t & 3;
        const ushort_t* Asl = &As[slot][0];
        const ushort_t* Bsl = &Bs[slot][0];
        const int nslot = (t + 3) & 3;
        const int kof   = (t + 3) * 32;

        // ---- reads for first MFMA cluster + stage A of tile t+3 ----
        bf16x8 bf[4], af0[4], af1[4];
        #pragma unroll
        for (int j = 0; j < 4; ++j)
            bf[j] = *reinterpret_cast<const bf16x8*>(Bsl + rdB + j * 16 * 32);
        #pragma unroll
        for (int i = 0; i < 4; ++i)
            af0[i] = *reinterpret_cast<const bf16x8*>(Asl + rdA + i * 16 * 32);
        if (t < 125) {
            GLDS16(gA0 + kof, &As[nslot][ldsOff0]);
            GLDS16(gA1 + kof, &As[nslot][ldsOff1]);
        }
        __builtin_amdgcn_s_setprio(1);
        #pragma unroll
        for (int i = 0; i < 4; ++i)
            #pragma unroll
            for (int j = 0; j < 4; ++j)
                acc[i][j] = __builtin_amdgcn_mfma_f32_16x16x32_bf16(
                    af0[i], bf[j], acc[i][j], 0, 0, 0);
        __builtin_amdgcn_s_setprio(0);

        // ---- reads for second MFMA cluster + stage B of tile t+3 ----
        #pragma unroll
        for (int i = 0; i < 4; ++i)
            af1[i] = *reinterpret_cast<const bf16x8*>(Asl + rdA + (64 + i * 16) * 32);
        if (t < 125) {
            GLDS16(gB0 + kof, &Bs[nslot][ldsOff0]);
            GLDS16(gB1 + kof, &Bs[nslot][ldsOff1]);
        }
        __builtin_amdgcn_s_setprio(1);
        #pragma unroll
        for (int i = 0; i < 4; ++i)
            #pragma unroll
            for (int j = 0; j < 4; ++j)
                acc[4 + i][j] = __builtin_amdgcn_mfma_f32_16x16x32_bf16(
                    af1[i], bf[j], acc[4 + i][j], 0, 0, 0);
        __builtin_amdgcn_s_setprio(0);

        // ---- tile-boundary sync: own prefetch counted, then one barrier ----
        if (t < 125)       asm volatile("s_waitcnt vmcnt(8)" ::: "memory");
        else if (t == 125) asm volatile("s_waitcnt vmcnt(4)" ::: "memory");
        else if (t == 126) asm volatile("s_waitcnt vmcnt(0)" ::: "memory");
        __builtin_amdgcn_s_barrier();
        __builtin_amdgcn_sched_barrier(0);
    }

    // epilogue: C/D layout col = lane&15, row = (lane>>4)*4 + v
    const int crow0 = m0 + wr * 128 + lq * 4;
    const int ccol0 = n0 + wc * 64 + ln15;
    #pragma unroll
    for (int j = 0; j < 4; ++j) {
        const int c = ccol0 + j * 16;
        const float bv = bias[c];
        #pragma unroll
        for (int i = 0; i < 8; ++i) {
            const int r0 = crow0 + i * 16;
            #pragma unroll
            for (int v = 0; v < 4; ++v)
                C[(size_t)(r0 + v) * 4096 + c] = acc[i][j][v] + bv;
        }
    }
}

// ---------------------------------------------------------------------------
extern "C" void kernel_launch(void* const* d_in, const int* in_sizes, int n_in,
                              void* d_out, int out_size, void* d_ws, size_t ws_size,
                              hipStream_t stream) {
    const float* x      = (const float*)d_in[0];   // [4,2048,4096] fp32
    const int*   q      = (const int*)d_in[1];     // [8388608] byte values
    const float* scales = (const float*)d_in[2];   // [262144]
    const float* bias   = (const float*)d_in[3];   // [4096]
    float* out = (float*)d_out;                    // [8192][4096] fp32

    ushort_t* xb = (ushort_t*)d_ws;                                     // 64 MB bf16 x
    ushort_t* Wt = (ushort_t*)((char*)d_ws + (size_t)64 * 1024 * 1024); // 32 MB bf16 W^T

    prep_kernel<<<17408, 256, 0, stream>>>(x, q, scales, xb, Wt);
    gemm_nf4_kernel<<<512, 512, 0, stream>>>(xb, Wt, bias, out);
}

// Round 17
// 292.744 us; speedup vs baseline: 1.0559x; 1.0559x over previous
//
#include <hip/hip_runtime.h>
#include <hip/hip_bf16.h>
#include <stdint.h>

typedef __bf16 bf16x8 __attribute__((ext_vector_type(8)));
typedef float f32x16 __attribute__((ext_vector_type(16)));
typedef unsigned short ushort_t;
typedef ushort_t ushort8 __attribute__((ext_vector_type(8)));

#define GLDS16(g, l) __builtin_amdgcn_global_load_lds(                          \
    (const __attribute__((address_space(1))) void*)(g),                         \
    (__attribute__((address_space(3))) void*)(l), 16, 0, 0)

__device__ __constant__ float NF4_LUT_C[16] = {
    -1.0f, -0.6961928009986877f, -0.5250730514526367f, -0.39491748809814453f,
    -0.28444138169288635f, -0.18477343022823334f, -0.09105003625154495f, 0.0f,
    0.07958029955625534f, 0.16093020141124725f, 0.24611230194568634f,
    0.33791524171829224f, 0.44070982933044434f, 0.5626170039176941f,
    0.7229568362236023f, 1.0f};

__device__ inline ushort_t f32_to_bf16(float f) {
    uint32_t u = __builtin_bit_cast(uint32_t, f);
    u += 0x7FFFu + ((u >> 16) & 1u);
    return (ushort_t)(u >> 16);
}

// Packed fragment layout: chunk (b, kb) = 1KB; lane l, elems e 0..7 hold
// value[row = b*32 + (l&31)][k = kb*16 + (l>>5)*8 + e].
// Flat ushort index: (b*256 + kb)*512 + l*8 + e.

// ---------------------------------------------------------------------------
// Merged prep (r14-verified best): blocks 0..8191 cast x -> packed A;
// blocks 8192..12287 NF4-dequant -> packed B. One grid overlaps both
// memory-bound phases across CUs (~8 us vs serial dispatches).
// ---------------------------------------------------------------------------
__global__ __launch_bounds__(256) void prep_kernel(
    const float* __restrict__ x, const int* __restrict__ q,
    const float* __restrict__ scales,
    ushort_t* __restrict__ A_pk, ushort_t* __restrict__ B_pk)
{
    __shared__ ushort_t lt[32][130];
    __shared__ float lut[16];
    __shared__ ushort_t tile[64][65];
    const int t   = threadIdx.x;
    const int bid = blockIdx.x;

    if (bid < 8192) {
        // ---------------- cast part ----------------
        const int mb = bid >> 5;
        const int kc = bid & 31;
        {
            const int rl = t >> 3;
            const int c0 = (t & 7) * 16;
            const float4* p = reinterpret_cast<const float4*>(
                x + (size_t)(mb * 32 + rl) * 4096 + kc * 128 + c0);
            #pragma unroll
            for (int qq = 0; qq < 4; ++qq) {
                float4 a = p[qq];
                lt[rl][c0 + qq * 4 + 0] = f32_to_bf16(a.x);
                lt[rl][c0 + qq * 4 + 1] = f32_to_bf16(a.y);
                lt[rl][c0 + qq * 4 + 2] = f32_to_bf16(a.z);
                lt[rl][c0 + qq * 4 + 3] = f32_to_bf16(a.w);
            }
        }
        __syncthreads();

        ushort_t* dst = A_pk + ((size_t)mb * 256 + kc * 8) * 512 + t * 16;
        #pragma unroll
        for (int h = 0; h < 2; ++h) {
            const int c  = 2 * t + h;
            const int kb = c >> 6;
            const int l  = c & 63;
            const int rl = l & 31;
            const int k0 = kb * 16 + (l >> 5) * 8;
            ushort8 v;
            #pragma unroll
            for (int e = 0; e < 8; ++e) v[e] = lt[rl][k0 + e];
            *reinterpret_cast<ushort8*>(dst + h * 8) = v;
        }
    } else {
        // ---------------- dequant part ----------------
        const int bid2 = bid - 8192;
        const int nt = bid2 & 63;
        const int kt = bid2 >> 6;
        if (t < 16) lut[t] = NF4_LUT_C[t];
        __syncthreads();

        #pragma unroll
        for (int L = t; L < 512; L += 256) {
            const int r  = L >> 3;
            const int qd = L & 7;
            const int k  = kt * 64 + r;
            const int4 e4 = *reinterpret_cast<const int4*>(q + (size_t)k * 2048 + nt * 32 + qd * 4);
            const float s = scales[k * 64 + nt];
            const int nb = qd * 8;
            int bts[4] = {e4.x, e4.y, e4.z, e4.w};
            #pragma unroll
            for (int e = 0; e < 4; ++e) {
                const int byte = bts[e];
                tile[r][nb + e * 2]     = f32_to_bf16(lut[(byte >> 4) & 0xF] * s);
                tile[r][nb + e * 2 + 1] = f32_to_bf16(lut[byte & 0xF] * s);
            }
        }
        __syncthreads();

        #pragma unroll
        for (int h = 0; h < 2; ++h) {
            const int c   = 2 * t + h;
            const int nbl = c >> 8;
            const int kbl = (c >> 6) & 3;
            const int l   = c & 63;
            const int nl  = nbl * 32 + (l & 31);
            const int k0  = kbl * 16 + (l >> 5) * 8;
            ushort8 v;
            #pragma unroll
            for (int e = 0; e < 8; ++e) v[e] = tile[k0 + e][nl];
            ushort_t* dst = B_pk + ((size_t)(nt * 2 + nbl) * 256 + kt * 4 + kbl) * 512 + l * 8;
            *reinterpret_cast<ushort8*>(dst) = v;
        }
    }
}

// ---------------------------------------------------------------------------
// GEMM (r14-verified best total): 256x256 tile, BK=32, 8 waves (2M x 4N),
// 32x32x16 MFMA. Packed-fragment LDS (zero conflicts, zero VALU addressing,
// coalesced 1KB staging chunks), 4-slot ring, depth-3 prefetch, counted
// vmcnt(8)/4/0, ONE barrier per K32-tile. 280.4 us, MfmaUtil 44.8%, ~1010 TF.
// ---------------------------------------------------------------------------
__global__ __launch_bounds__(512, 2) void gemm_nf4_kernel(
    const ushort_t* __restrict__ A_pk, const ushort_t* __restrict__ B_pk,
    const float* __restrict__ bias, float* __restrict__ C)
{
    __shared__ __align__(16) ushort_t As[4][8192];
    __shared__ __align__(16) ushort_t Bs[4][8192];

    const int tid  = threadIdx.x;
    const int lane = tid & 63;
    const int w8   = tid >> 6;       // 0..7
    const int wr   = w8 >> 2;        // 0..1 -> 128-row A strip
    const int wc   = w8 & 3;         // 0..3 -> 64-col B strip
    const int ln31 = lane & 31;
    const int lq2  = lane >> 5;      // 0..1

    // XCD-aware bijective swizzle (512 % 8 == 0)
    const int wg  = blockIdx.x;
    const int swz = (wg & 7) * 64 + (wg >> 3);
    const int m0  = (swz >> 4) * 256;   // 32 m-tiles
    const int n0  = (swz & 15) * 256;   // 16 n-tiles

    const ushort_t* gA = A_pk + ((size_t)(m0 >> 5) + w8) * (256 * 512) + lane * 8;
    const ushort_t* gB = B_pk + ((size_t)(n0 >> 5) + w8) * (256 * 512) + lane * 8;

    f32x16 acc[4][2];
    #pragma unroll
    for (int i = 0; i < 4; ++i)
        #pragma unroll
        for (int j = 0; j < 2; ++j)
            acc[i][j] = (f32x16){0.f};

    const int aBase = wr * 4096 + lane * 8;
    const int bBase = wc * 2048 + lane * 8;

    // prologue: stage tiles 0,1,2 into slots 0,1,2 (4 loads/wave each)
    #pragma unroll
    for (int tt = 0; tt < 3; ++tt) {
        #pragma unroll
        for (int kb = 0; kb < 2; ++kb) {
            GLDS16(gA + (tt * 2 + kb) * 512, &As[tt][(w8 * 2 + kb) * 512]);
            GLDS16(gB + (tt * 2 + kb) * 512, &Bs[tt][(w8 * 2 + kb) * 512]);
        }
    }
    asm volatile("s_waitcnt vmcnt(8)" ::: "memory");   // tile 0 landed
    __builtin_amdgcn_s_barrier();
    __builtin_amdgcn_sched_barrier(0);

    for (int t = 0; t < 128; ++t) {
        const int slot  = t & 3;
        const int nslot = (t + 3) & 3;
        const ushort_t* Asl = &As[slot][aBase];
        const ushort_t* Bsl = &Bs[slot][bBase];
        const int kof = (t + 3) * 1024;

        // ---- kk = 0: frag reads + stage A chunks of tile t+3 + 8 MFMA ----
        bf16x8 af0[4], bf0[2], af1[4], bf1[2];
        #pragma unroll
        for (int i = 0; i < 4; ++i)
            af0[i] = *reinterpret_cast<const bf16x8*>(Asl + i * 1024);
        #pragma unroll
        for (int j = 0; j < 2; ++j)
            bf0[j] = *reinterpret_cast<const bf16x8*>(Bsl + j * 1024);
        if (t < 125) {
            GLDS16(gA + kof,       &As[nslot][(w8 * 2) * 512]);
            GLDS16(gA + kof + 512, &As[nslot][(w8 * 2 + 1) * 512]);
        }
        __builtin_amdgcn_s_setprio(1);
        #pragma unroll
        for (int i = 0; i < 4; ++i)
            #pragma unroll
            for (int j = 0; j < 2; ++j)
                acc[i][j] = __builtin_amdgcn_mfma_f32_32x32x16_bf16(
                    af0[i], bf0[j], acc[i][j], 0, 0, 0);
        __builtin_amdgcn_s_setprio(0);

        // ---- kk = 1: frag reads + stage B chunks of tile t+3 + 8 MFMA ----
        #pragma unroll
        for (int i = 0; i < 4; ++i)
            af1[i] = *reinterpret_cast<const bf16x8*>(Asl + i * 1024 + 512);
        #pragma unroll
        for (int j = 0; j < 2; ++j)
            bf1[j] = *reinterpret_cast<const bf16x8*>(Bsl + j * 1024 + 512);
        if (t < 125) {
            GLDS16(gB + kof,       &Bs[nslot][(w8 * 2) * 512]);
            GLDS16(gB + kof + 512, &Bs[nslot][(w8 * 2 + 1) * 512]);
        }
        __builtin_amdgcn_s_setprio(1);
        #pragma unroll
        for (int i = 0; i < 4; ++i)
            #pragma unroll
            for (int j = 0; j < 2; ++j)
                acc[i][j] = __builtin_amdgcn_mfma_f32_32x32x16_bf16(
                    af1[i], bf1[j], acc[i][j], 0, 0, 0);
        __builtin_amdgcn_s_setprio(0);

        // ---- tile boundary: own prefetch counted, one barrier ----
        if (t < 125)       asm volatile("s_waitcnt vmcnt(8)" ::: "memory");
        else if (t == 125) asm volatile("s_waitcnt vmcnt(4)" ::: "memory");
        else if (t == 126) asm volatile("s_waitcnt vmcnt(0)" ::: "memory");
        __builtin_amdgcn_s_barrier();
        __builtin_amdgcn_sched_barrier(0);
    }

    // epilogue: 32x32 C/D layout col = lane&31, row = (reg&3)+8*(reg>>2)+4*lq2
    const int crow_b = m0 + wr * 128 + lq2 * 4;
    const int ccol_b = n0 + wc * 64 + ln31;
    #pragma unroll
    for (int j = 0; j < 2; ++j) {
        const int c = ccol_b + j * 32;
        const float bv = bias[c];
        #pragma unroll
        for (int i = 0; i < 4; ++i) {
            #pragma unroll
            for (int reg = 0; reg < 16; ++reg) {
                const int r = crow_b + i * 32 + (reg & 3) + 8 * (reg >> 2);
                C[(size_t)r * 4096 + c] = acc[i][j][reg] + bv;
            }
        }
    }
}

// ---------------------------------------------------------------------------
extern "C" void kernel_launch(void* const* d_in, const int* in_sizes, int n_in,
                              void* d_out, int out_size, void* d_ws, size_t ws_size,
                              hipStream_t stream) {
    const float* x      = (const float*)d_in[0];   // [4,2048,4096] fp32
    const int*   q      = (const int*)d_in[1];     // [8388608] byte values
    const float* scales = (const float*)d_in[2];   // [262144]
    const float* bias   = (const float*)d_in[3];   // [4096]
    float* out = (float*)d_out;                    // [8192][4096] fp32

    ushort_t* A_pk = (ushort_t*)d_ws;                                     // 64 MB packed x
    ushort_t* B_pk = (ushort_t*)((char*)d_ws + (size_t)64 * 1024 * 1024); // 32 MB packed W

    prep_kernel<<<12288, 256, 0, stream>>>(x, q, scales, A_pk, B_pk);
    gemm_nf4_kernel<<<512, 512, 0, stream>>>(A_pk, B_pk, bias, out);
}